// Round 10
// baseline (322.084 us; speedup 1.0000x reference)
//
#include <hip/hip_runtime.h>
#include <math.h>

#define HEADS 4
#define BATCH 8
#define SEQ   1024
#define CH    256
#define DH    64
#define RB    16          // q rows per wave

typedef float  floatx4  __attribute__((ext_vector_type(4)));
typedef short  shortx8  __attribute__((ext_vector_type(8)));
typedef short  shortx4  __attribute__((ext_vector_type(4)));

__device__ __forceinline__ unsigned short f2bf(float f) {
    unsigned u = __float_as_uint(f);
    unsigned r = u + 0x7FFFu + ((u >> 16) & 1u);   // RNE
    return (unsigned short)(r >> 16);
}
__device__ __forceinline__ shortx8 pack8(float4 a, float4 b) {
    shortx8 r;
    r[0] = (short)f2bf(a.x); r[1] = (short)f2bf(a.y);
    r[2] = (short)f2bf(a.z); r[3] = (short)f2bf(a.w);
    r[4] = (short)f2bf(b.x); r[5] = (short)f2bf(b.y);
    r[6] = (short)f2bf(b.z); r[7] = (short)f2bf(b.w);
    return r;
}

// ---- prologue staging (q PRE-SCALED by 0.125: folds softmax temperature
// into the QK MFMA — exact in bf16, pow2).
// qb/kb: bf16 [B,N,C].  vt: bf16 V transposed per head [b][h][d][n].
// pm: pm[((b*SEQ+row)<<5) + w*4 + qd], bit (mc*4+r) =
//     mask[b][row][mc*128 + w*16 + qd*4 + r].
__global__ __launch_bounds__(256)
void prep(const float* __restrict__ q, const float* __restrict__ k,
          const float* __restrict__ v, const void* __restrict__ maskp,
          unsigned short* __restrict__ qb, unsigned short* __restrict__ kb,
          unsigned short* __restrict__ vt, unsigned* __restrict__ pm)
{
    __shared__ unsigned short tl[64][68];
    const int t = threadIdx.x;
    const int bid = blockIdx.x;
    if (bid < 2048) {                       // q (0..1023) / k (1024..2047)
        const float* src = (bid < 1024) ? q : k;
        unsigned short* dst = (bid < 1024) ? qb : kb;
        const float sc = (bid < 1024) ? 0.125f : 1.0f;
        size_t idx = (size_t)(bid & 1023) * 2048 + (size_t)t * 8;
        float4 a = *(const float4*)(src + idx);
        float4 b = *(const float4*)(src + idx + 4);
        a.x *= sc; a.y *= sc; a.z *= sc; a.w *= sc;
        b.x *= sc; b.y *= sc; b.z *= sc; b.w *= sc;
        *(shortx8*)(dst + idx) = pack8(a, b);
        return;
    }
    if (bid < 2560) {
        // V transpose-convert: block = (b, h, 64-row n-tile)
        const int vb = bid - 2048;
        const int nt = vb & 15, h = (vb >> 4) & 3, b = vb >> 6;
        const int n0 = nt * 64;
        const float* vsrc = v + ((size_t)(b * SEQ + n0)) * CH + h * DH;
        #pragma unroll
        for (int it = 0; it < 4; ++it) {
            int fid = it * 256 + t;
            int n = fid >> 4, cc = (fid & 15) * 4;
            float4 x = *(const float4*)(vsrc + (size_t)n * CH + cc);
            tl[n][cc]     = f2bf(x.x);
            tl[n][cc + 1] = f2bf(x.y);
            tl[n][cc + 2] = f2bf(x.z);
            tl[n][cc + 3] = f2bf(x.w);
        }
        __syncthreads();
        unsigned short* vout = vt + ((size_t)((b * HEADS + h) * DH)) * SEQ + n0;
        #pragma unroll
        for (int it = 0; it < 2; ++it) {
            int cid = it * 256 + t;
            int d = cid >> 3, nc = cid & 7;
            shortx8 r;
            #pragma unroll
            for (int j = 0; j < 8; ++j) r[j] = (short)tl[nc * 8 + j][d];
            *(shortx8*)(vout + (size_t)d * SEQ + nc * 8) = r;
        }
        return;
    }
    // ---- mask pack: block = (b, 8-row group); 256 thr = sub(8) x wq(32) ----
    const int vb2 = bid - 2560;              // 0..1023
    const int b = vb2 >> 7, rg = vb2 & 127;
    const int sub = t >> 5, wq = t & 31;     // wq = w*4+qd
    const int row = rg * 8 + sub;
    const int w_ = wq >> 2, qd_ = wq & 3;
    int fl;
    {
        const unsigned* mw = (const unsigned*)maskp;
        const int lane = t & 63;
        int found = 0;
        #pragma unroll
        for (int j = 0; j < 16; ++j)
            if (mw[lane * 16 + j] & 0xFFFFFF00u) found = 1;
        fl = (__ballot(found != 0) != 0ULL) ? 1 : 0;   // 1 => byte mask
    }
    const unsigned char* m8  = (const unsigned char*)maskp;
    const int*           m32 = (const int*)maskp;
    unsigned u = 0;
    #pragma unroll
    for (int mc = 0; mc < 8; ++mc) {
        #pragma unroll
        for (int r = 0; r < 4; ++r) {
            size_t idx = ((size_t)(b * SEQ + row)) * SEQ
                       + mc * 128 + w_ * 16 + qd_ * 4 + r;
            int mk = fl ? (int)m8[idx] : m32[idx];
            u |= (mk ? 1u : 0u) << (mc * 4 + r);
        }
    }
    pm[(((size_t)b * SEQ + row) << 5) + wq] = u;
}

// R9: one INDEPENDENT wave per (b, h, 16-row q-tile) — 2048 waves, zero
// inter-wave coupling, no 8-wave barriers, no phase convoy.  Scores are
// bounded (|s| <~ 10), so exp needs no max subtraction (softmax is
// shift-invariant) -> the row sum accumulates in registers in ONE streaming
// pass.  Pass B recomputes scores (MFMA is ~3% utilized; recompute is free),
// writes normalized p_attn directly from registers, and feeds PV via a tiny
// per-wave LDS double-buffer (wave-internal syncthreads, 1-wave blocks).
__global__ __launch_bounds__(64)
void attn_wave(const unsigned short* __restrict__ qb,
               const unsigned short* __restrict__ kbf,
               const unsigned short* __restrict__ vt,
               const unsigned* __restrict__ pm,
               const float* __restrict__ dis, float* __restrict__ out,
               float* __restrict__ pout)
{
    __shared__ unsigned short ps[2][16][40];   // 2.5 KB P-staging (pad 40)

    const int t   = threadIdx.x;               // 0..63 (one wave)
    const int bid = blockIdx.x;                // 0..2047
    const int b   = bid & (BATCH - 1);         // XCD-pinned batch
    const int h   = (bid >> 3) & (HEADS - 1);
    const int n0  = (bid >> 5) * RB;
    const int ln  = t & 15;                    // q-row owned by this lane
    const int qd  = t >> 4;                    // col subgroup / k-slice

    // Q B-frags (pre-scaled by 0.125)
    const unsigned short* qrow = qb + ((size_t)(b * SEQ + n0 + ln)) * CH + h * DH;
    shortx8 aq0 = *(const shortx8*)(qrow + qd * 8);
    shortx8 aq1 = *(const shortx8*)(qrow + 32 + qd * 8);

    const unsigned short* kbase = kbf + ((size_t)(b * SEQ)) * CH + h * DH;
    const unsigned short* vbase = vt + ((size_t)((b * HEADS + h) * DH)) * SEQ;
    const float* disrow =
        dis + ((size_t)(b * SEQ + n0 + ln)) * SEQ + qd * 4;
    const unsigned* pmrow = pm + (((size_t)(b * SEQ + n0 + ln)) << 5) + qd;

    // ---- Pass A: stream all 64 col-tiles, accumulate row exp-sum only ----
    float sum = 0.f;
    for (int wg = 0; wg < 8; ++wg) {
        const unsigned mw = pmrow[wg * 4];
        #pragma unroll 4
        for (int mc = 0; mc < 8; ++mc) {
            const int cb = mc * 128 + wg * 16;
            const unsigned short* krow = kbase + (size_t)(cb + ln) * CH;
            shortx8 kf0 = *(const shortx8*)(krow + qd * 8);
            shortx8 kf1 = *(const shortx8*)(krow + 32 + qd * 8);
            float4 dv = *(const float4*)(disrow + cb);
            floatx4 acc = {0.f, 0.f, 0.f, 0.f};
            acc = __builtin_amdgcn_mfma_f32_16x16x32_bf16(kf0, aq0, acc, 0, 0, 0);
            acc = __builtin_amdgcn_mfma_f32_16x16x32_bf16(kf1, aq1, acc, 0, 0, 0);
            float x0 = __expf(fmaf(dv.x, 0.125f, acc[0]));
            float x1 = __expf(fmaf(dv.y, 0.125f, acc[1]));
            float x2 = __expf(fmaf(dv.z, 0.125f, acc[2]));
            float x3 = __expf(fmaf(dv.w, 0.125f, acc[3]));
            if ((mw >> (mc * 4 + 0)) & 1u) x0 = 0.f;
            if ((mw >> (mc * 4 + 1)) & 1u) x1 = 0.f;
            if ((mw >> (mc * 4 + 2)) & 1u) x2 = 0.f;
            if ((mw >> (mc * 4 + 3)) & 1u) x3 = 0.f;
            sum += x0 + x1 + x2 + x3;
        }
    }
    sum += __shfl_xor(sum, 16);        // reduce across qd groups: row total
    sum += __shfl_xor(sum, 32);
    const float inv = 1.0f / sum;      // all 4 qd lanes of ln share row ln's inv

    // ---- Pass B: recompute scores per col-pair; write p_attn; PV ----
    floatx4 o0 = {0.f,0.f,0.f,0.f}, o1 = {0.f,0.f,0.f,0.f};
    floatx4 o2 = {0.f,0.f,0.f,0.f}, o3 = {0.f,0.f,0.f,0.f};
    float* prow = pout + ((size_t)((h * BATCH + b) * SEQ + n0 + ln)) * SEQ
                + qd * 4;
    int par = 0;
    for (int wp = 0; wp < 4; ++wp) {
        const unsigned mw0 = pmrow[(2 * wp) * 4];
        const unsigned mw1 = pmrow[(2 * wp + 1) * 4];
        #pragma unroll 2
        for (int mc = 0; mc < 8; ++mc) {
            const int cb = mc * 128 + wp * 32;      // pair: tiles cb, cb+16
            // V loads first (independent of everything below)
            const unsigned short* vk = vbase + cb + qd * 8;
            shortx8 vf0 = *(const shortx8*)(vk + (size_t)(0 * 16 + ln) * SEQ);
            shortx8 vf1 = *(const shortx8*)(vk + (size_t)(1 * 16 + ln) * SEQ);
            shortx8 vf2 = *(const shortx8*)(vk + (size_t)(2 * 16 + ln) * SEQ);
            shortx8 vf3 = *(const shortx8*)(vk + (size_t)(3 * 16 + ln) * SEQ);
            // scores for both tiles
            const unsigned short* kr0 = kbase + (size_t)(cb + ln) * CH;
            const unsigned short* kr1 = kbase + (size_t)(cb + 16 + ln) * CH;
            shortx8 k00 = *(const shortx8*)(kr0 + qd * 8);
            shortx8 k01 = *(const shortx8*)(kr0 + 32 + qd * 8);
            shortx8 k10 = *(const shortx8*)(kr1 + qd * 8);
            shortx8 k11 = *(const shortx8*)(kr1 + 32 + qd * 8);
            float4 dv0 = *(const float4*)(disrow + cb);
            float4 dv1 = *(const float4*)(disrow + cb + 16);
            floatx4 a0 = {0.f,0.f,0.f,0.f}, a1 = {0.f,0.f,0.f,0.f};
            a0 = __builtin_amdgcn_mfma_f32_16x16x32_bf16(k00, aq0, a0, 0, 0, 0);
            a0 = __builtin_amdgcn_mfma_f32_16x16x32_bf16(k01, aq1, a0, 0, 0, 0);
            a1 = __builtin_amdgcn_mfma_f32_16x16x32_bf16(k10, aq0, a1, 0, 0, 0);
            a1 = __builtin_amdgcn_mfma_f32_16x16x32_bf16(k11, aq1, a1, 0, 0, 0);
            float p0[4], p1[4];
            #pragma unroll
            for (int r = 0; r < 4; ++r) {
                float e0 = __expf(fmaf(((const float*)&dv0)[r], 0.125f, a0[r]));
                float e1 = __expf(fmaf(((const float*)&dv1)[r], 0.125f, a1[r]));
                if ((mw0 >> (mc * 4 + r)) & 1u) e0 = 0.f;
                if ((mw1 >> (mc * 4 + r)) & 1u) e1 = 0.f;
                p0[r] = e0; p1[r] = e1;
            }
            // normalized p_attn straight from registers (two float4)
            float4 pv0 = { p0[0]*inv, p0[1]*inv, p0[2]*inv, p0[3]*inv };
            float4 pv1 = { p1[0]*inv, p1[1]*inv, p1[2]*inv, p1[3]*inv };
            *(float4*)(prow + cb)      = pv0;
            *(float4*)(prow + cb + 16) = pv1;
            // stage unnormalized exp as bf16 for the PV A-fragment
            shortx4 e0, e1;
            e0[0] = (short)f2bf(p0[0]); e0[1] = (short)f2bf(p0[1]);
            e0[2] = (short)f2bf(p0[2]); e0[3] = (short)f2bf(p0[3]);
            e1[0] = (short)f2bf(p1[0]); e1[1] = (short)f2bf(p1[1]);
            e1[2] = (short)f2bf(p1[2]); e1[3] = (short)f2bf(p1[3]);
            *(shortx4*)&ps[par][ln][qd * 4]      = e0;
            *(shortx4*)&ps[par][ln][16 + qd * 4] = e1;
            __syncthreads();   // 1-wave block: lgkmcnt drain + trivial barrier
            shortx8 af = *(const shortx8*)&ps[par][ln][qd * 8];
            o0 = __builtin_amdgcn_mfma_f32_16x16x32_bf16(af, vf0, o0, 0, 0, 0);
            o1 = __builtin_amdgcn_mfma_f32_16x16x32_bf16(af, vf1, o1, 0, 0, 0);
            o2 = __builtin_amdgcn_mfma_f32_16x16x32_bf16(af, vf2, o2, 0, 0, 0);
            o3 = __builtin_amdgcn_mfma_f32_16x16x32_bf16(af, vf3, o3, 0, 0, 0);
            par ^= 1;
        }
    }

    // ---- epilogue: O rows = qd*4+dr, cols dt*16+ln ----
    const float invq0 = __shfl(inv, qd * 4 + 0);
    const float invq1 = __shfl(inv, qd * 4 + 1);
    const float invq2 = __shfl(inv, qd * 4 + 2);
    const float invq3 = __shfl(inv, qd * 4 + 3);
    #pragma unroll
    for (int dr = 0; dr < 4; ++dr) {
        const float iq = (dr == 0) ? invq0 : (dr == 1) ? invq1
                       : (dr == 2) ? invq2 : invq3;
        float* orow = out + ((size_t)(b * SEQ + n0 + qd * 4 + dr)) * CH
                    + h * DH + ln;
        orow[0]  = o0[dr] * iq;
        orow[16] = o1[dr] * iq;
        orow[32] = o2[dr] * iq;
        orow[48] = o3[dr] * iq;
    }
}

extern "C" void kernel_launch(void* const* d_in, const int* in_sizes, int n_in,
                              void* d_out, int out_size, void* d_ws, size_t ws_size,
                              hipStream_t stream) {
    const float* q    = (const float*)d_in[0];
    const float* k    = (const float*)d_in[1];
    const float* v    = (const float*)d_in[2];
    const void*  mask = d_in[3];
    const float* dis  = (const float*)d_in[4];
    float* out  = (float*)d_out;
    float* pout = out + (size_t)BATCH * SEQ * CH;   // p_attn after out

    // workspace: qb | kb | vt (each 2M bf16 = 4 MB) | pm (1 MB) => 13 MB
    unsigned short* qb  = (unsigned short*)d_ws;
    unsigned short* kbw = qb  + (size_t)BATCH * SEQ * CH;
    unsigned short* vtw = kbw + (size_t)BATCH * SEQ * CH;
    unsigned*       pmw = (unsigned*)(vtw + (size_t)BATCH * SEQ * CH);
    (void)ws_size;

    prep<<<3584, 256, 0, stream>>>(q, k, v, mask, qb, kbw, vtw, pmw);
    attn_wave<<<HEADS * BATCH * (SEQ / RB), 64, 0, stream>>>(
        qb, kbw, vtw, pmw, dis, out, pout);
}